// Round 5
// baseline (1756.263 us; speedup 1.0000x reference)
//
#include <hip/hip_runtime.h>
#include <hip/hip_fp16.h>

#define N_B 8
#define P 2048
#define NP (N_B * P)          // 16384
#define EPS 0.1f
#define IEPS 10.0f            // 1/eps
#define LOG_EPS 1e-8f
#define MAX_ITER 50

typedef float f4 __attribute__((ext_vector_type(4)));
typedef unsigned long long u64s;   // scalar 8B packet for NT stores

// ---------------------------------------------------------------------------
// init: s0 = nu + LOG_EPS  (so a = nu'/s0 == 1, i.e. v=0)
// ---------------------------------------------------------------------------
__global__ __launch_bounds__(256) void k_init(const float* __restrict__ nu,
                                              float* __restrict__ s0) {
    int idx = blockIdx.x * 256 + threadIdx.x;   // grid = NP/256 = 64 blocks
    s0[idx] = nu[idx] + LOG_EPS;
}

// ---------------------------------------------------------------------------
// build K = exp(-C/eps) fp16 (fallback tier: K only)
// ---------------------------------------------------------------------------
__global__ __launch_bounds__(256) void k_build(const float* __restrict__ C,
                                               __half* __restrict__ K) {
    size_t idx = ((size_t)blockIdx.x * 256 + threadIdx.x) * 4;
    float4 c = *(const float4*)(C + idx);
    __half2 h01 = __floats2half2_rn(expf(-IEPS * c.x), expf(-IEPS * c.y));
    __half2 h23 = __floats2half2_rn(expf(-IEPS * c.z), expf(-IEPS * c.w));
    *(__half2*)(K + idx)     = h01;
    *(__half2*)(K + idx + 2) = h23;
}

// ---------------------------------------------------------------------------
// build K AND K^T in fp16, 64x64 tiles via LDS (one-time)
// NT-channel split: ODD rows of each output matrix are stored with
// nontemporal hints (as scalar u64 — builtin rejects HIP vector classes)
// -> never allocate in L3 -> stream from HBM in k_pass. EVEN rows stored
// normally -> L3-resident. 50/50 split of the 134 MB.
// grid = N_B * 32 * 32 blocks, 256 threads
// ---------------------------------------------------------------------------
__global__ __launch_bounds__(256) void k_build2(const float* __restrict__ C,
                                                __half* __restrict__ K,
                                                __half* __restrict__ KT) {
    __shared__ __half sh[64][72];            // +8 halfs pad breaks bank stride
    int b = blockIdx.x;
    const int tj = b & 31; b >>= 5;
    const int ti = b & 31; b >>= 5;
    const int n  = b;
    const int tid = threadIdx.x;
    const int lr = tid >> 4;                 // 0..15
    const int lc = (tid & 15) * 4;           // 0,4,...,60
    #pragma unroll
    for (int e = 0; e < 4; ++e) {
        const int r = e * 16 + lr;
        const size_t off = ((size_t)(n * P + ti * 64 + r)) * P + tj * 64 + lc;
        f4 c4 = *(const f4*)(C + off);
        __half h0 = __float2half(expf(-IEPS * c4.x));
        __half h1 = __float2half(expf(-IEPS * c4.y));
        __half h2 = __float2half(expf(-IEPS * c4.z));
        __half h3 = __float2half(expf(-IEPS * c4.w));
        union { __half2 h[2]; u64s u; } pk;
        pk.h[0] = __halves2half2(h0, h1);
        pk.h[1] = __halves2half2(h2, h3);
        if (r & 1) {        // K row (ti*64+r): odd -> HBM channel (no L3 alloc)
            __builtin_nontemporal_store(pk.u, (u64s*)(K + off));
        } else {            // even -> L3 channel
            *(u64s*)(K + off) = pk.u;
        }
        sh[r][lc] = h0; sh[r][lc + 1] = h1; sh[r][lc + 2] = h2; sh[r][lc + 3] = h3;
    }
    __syncthreads();
    #pragma unroll
    for (int e = 0; e < 4; ++e) {
        const int r = e * 16 + lr;           // KT row within tile = original col
        const size_t off = ((size_t)(n * P + tj * 64 + r)) * P + ti * 64 + lc;
        union { __half2 h[2]; u64s u; } pk;
        pk.h[0] = __halves2half2(sh[lc][r],     sh[lc + 1][r]);
        pk.h[1] = __halves2half2(sh[lc + 2][r], sh[lc + 3][r]);
        if (r & 1) {        // KT row (tj*64+r): odd -> HBM channel
            __builtin_nontemporal_store(pk.u, (u64s*)(KT + off));
        } else {
            *(u64s*)(KT + off) = pk.u;
        }
    }
}

// ---------------------------------------------------------------------------
// symmetric streaming pass over a row-major fp16 matrix (K or K^T).
// PASS=0 (row): vin=sA, stage a_j=nu'_j/sA_j, out w_i = mu'_i / (K a)_i
// PASS=1 (col): vin=w,  stage w_j directly,   out sB_i = (K^T w)_i  (no atomics)
// 8 matrix-rows per block, 2 per wave; vector register-cached (32 f32/lane),
// no LDS, no barriers; K loads 16 B/lane coalesced, NONTEMPORAL (preserves the
// odd-row-HBM / even-row-L3 channel split: hits still hit, misses don't
// allocate).
// ---------------------------------------------------------------------------
template <int PASS>
__global__ __launch_bounds__(256) void k_pass(const __half* __restrict__ Km,
                                              const float* __restrict__ mu,
                                              const float* __restrict__ nu,
                                              const float* __restrict__ vin,
                                              float* __restrict__ vout) {
    const int tid  = threadIdx.x;
    const int n    = blockIdx.x >> 8;        // 256 blocks per batch (P/8)
    const int r0   = (blockIdx.x & 255) * 8;
    const int wave = tid >> 6, lane = tid & 63;
    const float* vn  = vin + n * P;
    const float* nun = nu  + n * P;

    f4 areg[8];
    #pragma unroll
    for (int q = 0; q < 4; ++q) {
        const int j = q * 512 + lane * 8;
        f4 sv0 = *(const f4*)(vn + j);
        f4 sv1 = *(const f4*)(vn + j + 4);
        if (PASS == 0) {
            f4 nv0 = *(const f4*)(nun + j);
            f4 nv1 = *(const f4*)(nun + j + 4);
            f4 a0, a1;
            a0.x = (nv0.x + LOG_EPS) / sv0.x;
            a0.y = (nv0.y + LOG_EPS) / sv0.y;
            a0.z = (nv0.z + LOG_EPS) / sv0.z;
            a0.w = (nv0.w + LOG_EPS) / sv0.w;
            a1.x = (nv1.x + LOG_EPS) / sv1.x;
            a1.y = (nv1.y + LOG_EPS) / sv1.y;
            a1.z = (nv1.z + LOG_EPS) / sv1.z;
            a1.w = (nv1.w + LOG_EPS) / sv1.w;
            areg[2 * q] = a0; areg[2 * q + 1] = a1;
        } else {
            areg[2 * q] = sv0; areg[2 * q + 1] = sv1;
        }
    }

    #pragma unroll
    for (int rp = 0; rp < 2; ++rp) {
        const int i = r0 + wave + rp * 4;
        const size_t rowoff = (size_t)(n * P + i) * P;
        float sa = 0.f, sb = 0.f;
        #pragma unroll
        for (int q = 0; q < 4; ++q) {
            const int j = q * 512 + lane * 8;
            f4 kv = __builtin_nontemporal_load((const f4*)(Km + rowoff + j));
            const __half2* kh = (const __half2*)&kv;
            float2 f0 = __half22float2(kh[0]);
            float2 f1 = __half22float2(kh[1]);
            float2 f2 = __half22float2(kh[2]);
            float2 f3 = __half22float2(kh[3]);
            f4 a0 = areg[2 * q], a1 = areg[2 * q + 1];
            sa += f0.x * a0.x + f0.y * a0.y + f1.x * a0.z + f1.y * a0.w;
            sb += f2.x * a1.x + f2.y * a1.y + f3.x * a1.z + f3.y * a1.w;
        }
        float sum = sa + sb;
        #pragma unroll
        for (int off = 32; off > 0; off >>= 1) sum += __shfl_down(sum, off, 64);
        if (lane == 0) {
            if (PASS == 0) vout[n * P + i] = (mu[n * P + i] + LOG_EPS) / sum;
            else           vout[n * P + i] = sum;
        }
    }
}

// ---------------------------------------------------------------------------
// FALLBACK (ws too small for K^T): round-0 proven row/col kernels
// ---------------------------------------------------------------------------
template <bool USEK>
__global__ __launch_bounds__(256) void k_row(const __half* __restrict__ K,
                                             const float* __restrict__ C,
                                             const float* __restrict__ mu,
                                             const float* __restrict__ nu,
                                             const float* __restrict__ sA,
                                             float* __restrict__ sB,
                                             float* __restrict__ w) {
    __shared__ float a_sh[P];
    const int tid = threadIdx.x;
    if (blockIdx.x < NP / 256) sB[blockIdx.x * 256 + tid] = 0.f;

    const int n  = blockIdx.x >> 8;
    const int r0 = (blockIdx.x & 255) * 8;
    const float* sAn = sA + n * P;
    const float* nun = nu + n * P;
    for (int j = tid; j < P; j += 256)
        a_sh[j] = (nun[j] + LOG_EPS) / sAn[j];
    __syncthreads();

    const int wave = tid >> 6, lane = tid & 63;
    for (int rr = wave; rr < 8; rr += 4) {
        const int i = r0 + rr;
        const size_t rowoff = (size_t)(n * P + i) * P;
        float sum = 0.f;
        #pragma unroll
        for (int jj = 0; jj < P; jj += 256) {
            const int j = jj + lane * 4;
            float4 av = *(const float4*)&a_sh[j];
            float k0, k1, k2, k3;
            if (USEK) {
                const __half2* kp = (const __half2*)(K + rowoff + j);
                float2 f01 = __half22float2(kp[0]);
                float2 f23 = __half22float2(kp[1]);
                k0 = f01.x; k1 = f01.y; k2 = f23.x; k3 = f23.y;
            } else {
                float4 c4 = *(const float4*)(C + rowoff + j);
                k0 = expf(-IEPS * c4.x); k1 = expf(-IEPS * c4.y);
                k2 = expf(-IEPS * c4.z); k3 = expf(-IEPS * c4.w);
            }
            sum += k0 * av.x + k1 * av.y + k2 * av.z + k3 * av.w;
        }
        #pragma unroll
        for (int off = 32; off > 0; off >>= 1) sum += __shfl_down(sum, off, 64);
        if (lane == 0) w[n * P + i] = (mu[n * P + i] + LOG_EPS) / sum;
    }
}

template <bool USEK>
__global__ __launch_bounds__(256) void k_col(const __half* __restrict__ K,
                                             const float* __restrict__ C,
                                             const float* __restrict__ w,
                                             float* __restrict__ sB) {
    const int RPB = 64;
    int b = blockIdx.x;
    const int rc = b & 31; b >>= 5;
    const int jt = b & 3;  b >>= 2;
    const int n  = b;
    const int j  = jt * 512 + threadIdx.x * 2;
    const int i0 = rc * RPB;
    const float* wn = w + n * P;
    float s0 = 0.f, s1 = 0.f;
    if (USEK) {
        const __half2* kp = (const __half2*)(K + ((size_t)n * P + i0) * P + j);
        #pragma unroll 4
        for (int i = 0; i < RPB; ++i) {
            const float wi = wn[i0 + i];
            float2 kv = __half22float2(*kp);
            s0 += wi * kv.x; s1 += wi * kv.y;
            kp += P / 2;
        }
    } else {
        const float* cp = C + ((size_t)n * P + i0) * P + j;
        #pragma unroll 2
        for (int i = 0; i < RPB; ++i) {
            const float wi = wn[i0 + i];
            s0 += wi * expf(-IEPS * cp[0]);
            s1 += wi * expf(-IEPS * cp[1]);
            cp += P;
        }
    }
    atomicAdd(&sB[n * P + j],     s0);
    atomicAdd(&sB[n * P + j + 1], s1);
}

// ---------------------------------------------------------------------------
// a = nu'/s  (once, before final pass; written into dead s1)
// ---------------------------------------------------------------------------
__global__ __launch_bounds__(256) void k_a(const float* __restrict__ nu,
                                           const float* __restrict__ s,
                                           float* __restrict__ a) {
    int idx = blockIdx.x * 256 + threadIdx.x;
    a[idx] = (nu[idx] + LOG_EPS) / s[idx];
}

// ---------------------------------------------------------------------------
// final: pi = w_i * a_j * exp(-C/eps) (fp32 C), write pi + C copy,
// per-block cost partial -> part[g]  (no global atomics)
// ---------------------------------------------------------------------------
__global__ __launch_bounds__(256) void k_final(const float* __restrict__ C,
                                               const float* __restrict__ a,
                                               const float* __restrict__ w,
                                               float* __restrict__ part,
                                               float* __restrict__ out) {
    const int g   = blockIdx.x;              // NP blocks, one row each
    const int n   = g >> 11;
    const int tid = threadIdx.x;
    const float wi = w[g];
    const size_t rowoff = (size_t)g * P;
    const float* Crow = C + rowoff;
    const float* an   = a + (size_t)n * P;
    float* pi_out = out + N_B + rowoff;
    float* c_out  = out + N_B + (size_t)NP * P + rowoff;
    float cost = 0.f;
    #pragma unroll
    for (int jj = 0; jj < P; jj += 1024) {
        const int j = jj + tid * 4;
        f4 c4 = *(const f4*)(Crow + j);
        f4 a4 = *(const f4*)(an + j);
        f4 p;
        p.x = wi * a4.x * expf(-IEPS * c4.x);
        p.y = wi * a4.y * expf(-IEPS * c4.y);
        p.z = wi * a4.z * expf(-IEPS * c4.z);
        p.w = wi * a4.w * expf(-IEPS * c4.w);
        __builtin_nontemporal_store(p,  (f4*)(pi_out + j));
        __builtin_nontemporal_store(c4, (f4*)(c_out + j));
        cost += p.x * c4.x + p.y * c4.y + p.z * c4.z + p.w * c4.w;
    }
    const int wave = tid >> 6, lane = tid & 63;
    #pragma unroll
    for (int off = 32; off > 0; off >>= 1) cost += __shfl_down(cost, off, 64);
    __shared__ float red[4];
    if (lane == 0) red[wave] = cost;
    __syncthreads();
    if (tid == 0) part[g] = red[0] + red[1] + red[2] + red[3];
}

// ---------------------------------------------------------------------------
// cost reduce: out[n] = sum of 2048 per-row partials (deterministic)
// ---------------------------------------------------------------------------
__global__ __launch_bounds__(256) void k_reduce(const float* __restrict__ part,
                                                float* __restrict__ out) {
    const int n = blockIdx.x, tid = threadIdx.x;
    float s = 0.f;
    for (int b = tid; b < P; b += 256) s += part[(size_t)n * P + b];
    const int wave = tid >> 6, lane = tid & 63;
    #pragma unroll
    for (int off = 32; off > 0; off >>= 1) s += __shfl_down(s, off, 64);
    __shared__ float red[4];
    if (lane == 0) red[wave] = s;
    __syncthreads();
    if (tid == 0) out[n] = red[0] + red[1] + red[2] + red[3];
}

// ---------------------------------------------------------------------------
extern "C" void kernel_launch(void* const* d_in, const int* in_sizes, int n_in,
                              void* d_out, int out_size, void* d_ws, size_t ws_size,
                              hipStream_t stream) {
    const float* C  = (const float*)d_in[0];
    const float* mu = (const float*)d_in[1];
    const float* nu = (const float*)d_in[2];
    float* out = (float*)d_out;

    // ws layout: s0[NP] | s1[NP] | w[NP] | K[N*P*P] fp16 | KT[N*P*P] fp16
    float* s0 = (float*)d_ws;
    float* s1 = s0 + NP;
    float* w  = s1 + NP;
    __half* K  = (__half*)(w + NP);
    __half* KT = K + (size_t)NP * P;
    const size_t base   = 3ull * NP * sizeof(float);
    const size_t needK  = base + (size_t)NP * P * sizeof(__half);
    const size_t needKT = base + 2ull * (size_t)NP * P * sizeof(__half);
    const int tier = (ws_size >= needKT) ? 2 : (ws_size >= needK) ? 1 : 0;

    k_init<<<NP / 256, 256, 0, stream>>>(nu, s0);

    if (tier == 2) {
        k_build2<<<N_B * 32 * 32, 256, 0, stream>>>(C, K, KT);
        for (int t = 0; t < MAX_ITER; ++t) {
            float* sA = (t & 1) ? s1 : s0;
            float* sB = (t & 1) ? s0 : s1;
            k_pass<0><<<NP / 8, 256, 0, stream>>>(K,  mu, nu, sA, w);
            k_pass<1><<<NP / 8, 256, 0, stream>>>(KT, mu, nu, w,  sB);
        }
    } else if (tier == 1) {
        k_build<<<((size_t)NP * P) / 1024, 256, 0, stream>>>(C, K);
        for (int t = 0; t < MAX_ITER; ++t) {
            float* sA = (t & 1) ? s1 : s0;
            float* sB = (t & 1) ? s0 : s1;
            k_row<true><<<NP / 8, 256, 0, stream>>>(K, C, mu, nu, sA, sB, w);
            k_col<true><<<8 * 4 * 32, 256, 0, stream>>>(K, C, w, sB);
        }
    } else {
        for (int t = 0; t < MAX_ITER; ++t) {
            float* sA = (t & 1) ? s1 : s0;
            float* sB = (t & 1) ? s0 : s1;
            k_row<false><<<NP / 8, 256, 0, stream>>>(K, C, mu, nu, sA, sB, w);
            k_col<false><<<8 * 4 * 32, 256, 0, stream>>>(K, C, w, sB);
        }
    }

    // last col pass (t=49, odd) wrote s0 -> final a comes from s0.
    float* aBuf = s1;   // s1 dead after loop
    float* part = s0;   // s0 dead after k_a consumes it
    k_a<<<NP / 256, 256, 0, stream>>>(nu, s0, aBuf);
    k_final<<<NP, 256, 0, stream>>>(C, aBuf, w, part, out);
    k_reduce<<<N_B, 256, 0, stream>>>(part, out);
}

// Round 6
// 1342.437 us; speedup vs baseline: 1.3083x; 1.3083x over previous
//
#include <hip/hip_runtime.h>
#include <hip/hip_fp16.h>

#define N_B 8
#define P 2048
#define NP (N_B * P)          // 16384
#define EPS 0.1f
#define IEPS 10.0f            // 1/eps
#define LOG_EPS 1e-8f
#define MAX_ITER 50
#define RPB 16                // rows per fused block
#define NRB (P / RPB)         // 128 row-blocks per batch

typedef float f4 __attribute__((ext_vector_type(4)));

// ---------------------------------------------------------------------------
// init (fused tier): a_0 = nu'/s_0 = 1 exactly
// ---------------------------------------------------------------------------
__global__ __launch_bounds__(256) void k_init_one(float* __restrict__ a) {
    int idx = blockIdx.x * 256 + threadIdx.x;   // grid = NP/256
    a[idx] = 1.0f;
}

// init (fallback tiers): s0 = nu + LOG_EPS
__global__ __launch_bounds__(256) void k_init_nu(const float* __restrict__ nu,
                                                 float* __restrict__ s0) {
    int idx = blockIdx.x * 256 + threadIdx.x;
    s0[idx] = nu[idx] + LOG_EPS;
}

// ---------------------------------------------------------------------------
// build K = exp(-C/eps) fp16 (no transpose needed anymore)
// ---------------------------------------------------------------------------
__global__ __launch_bounds__(256) void k_build(const float* __restrict__ C,
                                               __half* __restrict__ K) {
    size_t idx = ((size_t)blockIdx.x * 256 + threadIdx.x) * 4;
    float4 c = *(const float4*)(C + idx);
    __half2 h01 = __floats2half2_rn(expf(-IEPS * c.x), expf(-IEPS * c.y));
    __half2 h23 = __floats2half2_rn(expf(-IEPS * c.z), expf(-IEPS * c.w));
    *(__half2*)(K + idx)     = h01;
    *(__half2*)(K + idx + 2) = h23;
}

// ---------------------------------------------------------------------------
// FUSED iteration kernel: reads K tile ONCE per iteration.
// Block = 16 rows x full P cols of one batch. grid = N_B * 128 = 1024 blocks.
// Phase A: stream 16 rows from global (staging into 64 KB LDS), row-dot with
//          register-cached a -> w_i = mu'_i / rowsum (computed in-block).
// Phase B: column partials from the LDS copy: part[n][rb][j] = sum_r w_r K[r][j]
//          (non-atomic, deterministic).
// ---------------------------------------------------------------------------
__global__ __launch_bounds__(256) void k_fused(const __half* __restrict__ Km,
                                               const float* __restrict__ mu,
                                               const float* __restrict__ a,
                                               float* __restrict__ w,
                                               float* __restrict__ part) {
    __shared__ __half ksh[RPB * P];          // 64 KB
    __shared__ float  w_sh[RPB];
    const int tid = threadIdx.x, wave = tid >> 6, lane = tid & 63;
    const int n  = blockIdx.x >> 7;          // 128 blocks per batch
    const int rb = blockIdx.x & 127;
    const int r0 = rb * RPB;
    const float* an = a + n * P;

    // register-cache the a vector (32 floats/lane; cols j = q*512 + lane*8)
    f4 areg[8];
    #pragma unroll
    for (int q = 0; q < 4; ++q) {
        const int j = q * 512 + lane * 8;
        areg[2 * q]     = *(const f4*)(an + j);
        areg[2 * q + 1] = *(const f4*)(an + j + 4);
    }

    // ---- phase A: each wave owns 4 rows ----
    #pragma unroll
    for (int rr = 0; rr < 4; ++rr) {
        const int r = wave * 4 + rr;         // 0..15
        const int i = r0 + r;
        const size_t rowoff = (size_t)(n * P + i) * P;
        float sa = 0.f, sb = 0.f;
        #pragma unroll
        for (int q = 0; q < 4; ++q) {
            const int j = q * 512 + lane * 8;
            f4 kv = *(const f4*)(Km + rowoff + j);    // 8 halfs, 16 B
            *(f4*)(ksh + r * P + j) = kv;             // stage for phase B
            const __half2* kh = (const __half2*)&kv;
            float2 f0 = __half22float2(kh[0]);
            float2 f1 = __half22float2(kh[1]);
            float2 f2 = __half22float2(kh[2]);
            float2 f3 = __half22float2(kh[3]);
            f4 a0 = areg[2 * q], a1 = areg[2 * q + 1];
            sa += f0.x * a0.x + f0.y * a0.y + f1.x * a0.z + f1.y * a0.w;
            sb += f2.x * a1.x + f2.y * a1.y + f3.x * a1.z + f3.y * a1.w;
        }
        float sum = sa + sb;
        #pragma unroll
        for (int off = 32; off > 0; off >>= 1) sum += __shfl_down(sum, off, 64);
        if (lane == 0) {
            float wi = (mu[n * P + i] + LOG_EPS) / sum;
            w_sh[r] = wi;
            w[n * P + i] = wi;               // needed by k_final after the loop
        }
    }
    __syncthreads();

    // ---- phase B: column partials (thread tid -> 8 adjacent cols) ----
    const int j0 = tid * 8;
    float s[8];
    #pragma unroll
    for (int q = 0; q < 8; ++q) s[q] = 0.f;
    #pragma unroll 4
    for (int r = 0; r < RPB; ++r) {
        const float wr = w_sh[r];
        f4 kv = *(const f4*)(ksh + r * P + j0);       // 16 B LDS, conflict-free
        const __half2* kh = (const __half2*)&kv;
        float2 f0 = __half22float2(kh[0]);
        float2 f1 = __half22float2(kh[1]);
        float2 f2 = __half22float2(kh[2]);
        float2 f3 = __half22float2(kh[3]);
        s[0] += wr * f0.x; s[1] += wr * f0.y;
        s[2] += wr * f1.x; s[3] += wr * f1.y;
        s[4] += wr * f2.x; s[5] += wr * f2.y;
        s[6] += wr * f3.x; s[7] += wr * f3.y;
    }
    float* pp = part + ((size_t)(n * NRB + rb)) * P + j0;
    f4 o0, o1;
    o0.x = s[0]; o0.y = s[1]; o0.z = s[2]; o0.w = s[3];
    o1.x = s[4]; o1.y = s[5]; o1.z = s[6]; o1.w = s[7];
    *(f4*)(pp)     = o0;
    *(f4*)(pp + 4) = o1;
}

// ---------------------------------------------------------------------------
// fold partials: a_j = nu'_j / sum_rb part[n][rb][j]
// grid = N_B * 32 blocks (64 cols each), 256 threads: tid=(rq 0..3, jj 0..63)
// ---------------------------------------------------------------------------
__global__ __launch_bounds__(256) void k_red(const float* __restrict__ part,
                                             const float* __restrict__ nu,
                                             float* __restrict__ aOut) {
    const int n  = blockIdx.x >> 5;
    const int jb = blockIdx.x & 31;
    const int tid = threadIdx.x;
    const int rq = tid >> 6, jj = tid & 63;
    const int j = jb * 64 + jj;
    const float* pp = part + (size_t)n * NRB * P + (size_t)(rq * 32) * P + j;
    float s = 0.f;
    #pragma unroll 8
    for (int r = 0; r < 32; ++r) s += pp[(size_t)r * P];
    __shared__ float red[4][64];
    red[rq][jj] = s;
    __syncthreads();
    if (rq == 0) {
        const float t = red[0][jj] + red[1][jj] + red[2][jj] + red[3][jj];
        const int idx = n * P + j;
        aOut[idx] = (nu[idx] + LOG_EPS) / t;
    }
}

// ---------------------------------------------------------------------------
// FALLBACK (ws too small): round-0 proven row/col kernels
// ---------------------------------------------------------------------------
template <bool USEK>
__global__ __launch_bounds__(256) void k_row(const __half* __restrict__ K,
                                             const float* __restrict__ C,
                                             const float* __restrict__ mu,
                                             const float* __restrict__ nu,
                                             const float* __restrict__ sA,
                                             float* __restrict__ sB,
                                             float* __restrict__ w) {
    __shared__ float a_sh[P];
    const int tid = threadIdx.x;
    if (blockIdx.x < NP / 256) sB[blockIdx.x * 256 + tid] = 0.f;

    const int n  = blockIdx.x >> 8;
    const int r0 = (blockIdx.x & 255) * 8;
    const float* sAn = sA + n * P;
    const float* nun = nu + n * P;
    for (int j = tid; j < P; j += 256)
        a_sh[j] = (nun[j] + LOG_EPS) / sAn[j];
    __syncthreads();

    const int wave = tid >> 6, lane = tid & 63;
    for (int rr = wave; rr < 8; rr += 4) {
        const int i = r0 + rr;
        const size_t rowoff = (size_t)(n * P + i) * P;
        float sum = 0.f;
        #pragma unroll
        for (int jj = 0; jj < P; jj += 256) {
            const int j = jj + lane * 4;
            float4 av = *(const float4*)&a_sh[j];
            float k0, k1, k2, k3;
            if (USEK) {
                const __half2* kp = (const __half2*)(K + rowoff + j);
                float2 f01 = __half22float2(kp[0]);
                float2 f23 = __half22float2(kp[1]);
                k0 = f01.x; k1 = f01.y; k2 = f23.x; k3 = f23.y;
            } else {
                float4 c4 = *(const float4*)(C + rowoff + j);
                k0 = expf(-IEPS * c4.x); k1 = expf(-IEPS * c4.y);
                k2 = expf(-IEPS * c4.z); k3 = expf(-IEPS * c4.w);
            }
            sum += k0 * av.x + k1 * av.y + k2 * av.z + k3 * av.w;
        }
        #pragma unroll
        for (int off = 32; off > 0; off >>= 1) sum += __shfl_down(sum, off, 64);
        if (lane == 0) w[n * P + i] = (mu[n * P + i] + LOG_EPS) / sum;
    }
}

template <bool USEK>
__global__ __launch_bounds__(256) void k_col(const __half* __restrict__ K,
                                             const float* __restrict__ C,
                                             const float* __restrict__ w,
                                             float* __restrict__ sB) {
    const int CRPB = 64;
    int b = blockIdx.x;
    const int rc = b & 31; b >>= 5;
    const int jt = b & 3;  b >>= 2;
    const int n  = b;
    const int j  = jt * 512 + threadIdx.x * 2;
    const int i0 = rc * CRPB;
    const float* wn = w + n * P;
    float s0 = 0.f, s1 = 0.f;
    if (USEK) {
        const __half2* kp = (const __half2*)(K + ((size_t)n * P + i0) * P + j);
        #pragma unroll 4
        for (int i = 0; i < CRPB; ++i) {
            const float wi = wn[i0 + i];
            float2 kv = __half22float2(*kp);
            s0 += wi * kv.x; s1 += wi * kv.y;
            kp += P / 2;
        }
    } else {
        const float* cp = C + ((size_t)n * P + i0) * P + j;
        #pragma unroll 2
        for (int i = 0; i < CRPB; ++i) {
            const float wi = wn[i0 + i];
            s0 += wi * expf(-IEPS * cp[0]);
            s1 += wi * expf(-IEPS * cp[1]);
            cp += P;
        }
    }
    atomicAdd(&sB[n * P + j],     s0);
    atomicAdd(&sB[n * P + j + 1], s1);
}

// ---------------------------------------------------------------------------
// a = nu'/s  (fallback epilogue only)
// ---------------------------------------------------------------------------
__global__ __launch_bounds__(256) void k_a(const float* __restrict__ nu,
                                           const float* __restrict__ s,
                                           float* __restrict__ a) {
    int idx = blockIdx.x * 256 + threadIdx.x;
    a[idx] = (nu[idx] + LOG_EPS) / s[idx];
}

// ---------------------------------------------------------------------------
// final: pi = w_i * a_j * exp(-C/eps) (fp32 C), write pi + C copy,
// per-block cost partial -> cpart[g]  (no global atomics)
// ---------------------------------------------------------------------------
__global__ __launch_bounds__(256) void k_final(const float* __restrict__ C,
                                               const float* __restrict__ a,
                                               const float* __restrict__ w,
                                               float* __restrict__ cpart,
                                               float* __restrict__ out) {
    const int g   = blockIdx.x;              // NP blocks, one row each
    const int n   = g >> 11;
    const int tid = threadIdx.x;
    const float wi = w[g];
    const size_t rowoff = (size_t)g * P;
    const float* Crow = C + rowoff;
    const float* an   = a + (size_t)n * P;
    float* pi_out = out + N_B + rowoff;
    float* c_out  = out + N_B + (size_t)NP * P + rowoff;
    float cost = 0.f;
    #pragma unroll
    for (int jj = 0; jj < P; jj += 1024) {
        const int j = jj + tid * 4;
        f4 c4 = *(const f4*)(Crow + j);
        f4 a4 = *(const f4*)(an + j);
        f4 p;
        p.x = wi * a4.x * expf(-IEPS * c4.x);
        p.y = wi * a4.y * expf(-IEPS * c4.y);
        p.z = wi * a4.z * expf(-IEPS * c4.z);
        p.w = wi * a4.w * expf(-IEPS * c4.w);
        __builtin_nontemporal_store(p,  (f4*)(pi_out + j));
        __builtin_nontemporal_store(c4, (f4*)(c_out + j));
        cost += p.x * c4.x + p.y * c4.y + p.z * c4.z + p.w * c4.w;
    }
    const int wave = tid >> 6, lane = tid & 63;
    #pragma unroll
    for (int off = 32; off > 0; off >>= 1) cost += __shfl_down(cost, off, 64);
    __shared__ float red[4];
    if (lane == 0) red[wave] = cost;
    __syncthreads();
    if (tid == 0) cpart[g] = red[0] + red[1] + red[2] + red[3];
}

// ---------------------------------------------------------------------------
// cost reduce: out[n] = sum of 2048 per-row partials (deterministic)
// ---------------------------------------------------------------------------
__global__ __launch_bounds__(256) void k_reduce(const float* __restrict__ cpart,
                                                float* __restrict__ out) {
    const int n = blockIdx.x, tid = threadIdx.x;
    float s = 0.f;
    for (int b = tid; b < P; b += 256) s += cpart[(size_t)n * P + b];
    const int wave = tid >> 6, lane = tid & 63;
    #pragma unroll
    for (int off = 32; off > 0; off >>= 1) s += __shfl_down(s, off, 64);
    __shared__ float red[4];
    if (lane == 0) red[wave] = s;
    __syncthreads();
    if (tid == 0) out[n] = red[0] + red[1] + red[2] + red[3];
}

// ---------------------------------------------------------------------------
extern "C" void kernel_launch(void* const* d_in, const int* in_sizes, int n_in,
                              void* d_out, int out_size, void* d_ws, size_t ws_size,
                              hipStream_t stream) {
    const float* C  = (const float*)d_in[0];
    const float* mu = (const float*)d_in[1];
    const float* nu = (const float*)d_in[2];
    float* out = (float*)d_out;

    // ws layout: v0[NP] | v1[NP] | v2[NP] | part8[N_B*NRB*P] | K[N*P*P] fp16
    float* v0 = (float*)d_ws;
    float* v1 = v0 + NP;
    float* v2 = v1 + NP;
    float* part8 = v2 + NP;
    __half* K = (__half*)(part8 + (size_t)N_B * NRB * P);
    const size_t base     = 3ull * NP * sizeof(float);
    const size_t needK    = base + (size_t)NP * P * sizeof(__half);
    const size_t needFuse = base + (size_t)N_B * NRB * P * sizeof(float)
                                 + (size_t)NP * P * sizeof(__half);
    // fallback tier-1 places K right after the 3 vectors
    __half* K1 = (__half*)(v2 + NP);
    const int tier = (ws_size >= needFuse) ? 2 : (ws_size >= needK) ? 1 : 0;

    if (tier == 2) {
        k_init_one<<<NP / 256, 256, 0, stream>>>(v0);          // a_0 = 1
        k_build<<<((size_t)NP * P) / 1024, 256, 0, stream>>>(C, K);
        for (int t = 0; t < MAX_ITER; ++t) {
            k_fused<<<N_B * NRB, 256, 0, stream>>>(K, mu, v0, v1, part8);
            k_red<<<N_B * 32, 256, 0, stream>>>(part8, nu, v0);
        }
        // v1 = w_49, v0 = a_50
        k_final<<<NP, 256, 0, stream>>>(C, v0, v1, v2, out);
        k_reduce<<<N_B, 256, 0, stream>>>(v2, out);
    } else if (tier == 1) {
        k_init_nu<<<NP / 256, 256, 0, stream>>>(nu, v0);
        k_build<<<((size_t)NP * P) / 1024, 256, 0, stream>>>(C, K1);
        for (int t = 0; t < MAX_ITER; ++t) {
            float* sA = (t & 1) ? v1 : v0;
            float* sB = (t & 1) ? v0 : v1;
            k_row<true><<<NP / 8, 256, 0, stream>>>(K1, C, mu, nu, sA, sB, v2);
            k_col<true><<<8 * 4 * 32, 256, 0, stream>>>(K1, C, v2, sB);
        }
        k_a<<<NP / 256, 256, 0, stream>>>(nu, v0, v1);
        k_final<<<NP, 256, 0, stream>>>(C, v1, v2, v0, out);
        k_reduce<<<N_B, 256, 0, stream>>>(v0, out);
    } else {
        k_init_nu<<<NP / 256, 256, 0, stream>>>(nu, v0);
        for (int t = 0; t < MAX_ITER; ++t) {
            float* sA = (t & 1) ? v1 : v0;
            float* sB = (t & 1) ? v0 : v1;
            k_row<false><<<NP / 8, 256, 0, stream>>>(nullptr, C, mu, nu, sA, sB, v2);
            k_col<false><<<8 * 4 * 32, 256, 0, stream>>>(nullptr, C, v2, sB);
        }
        k_a<<<NP / 256, 256, 0, stream>>>(nu, v0, v1);
        k_final<<<NP, 256, 0, stream>>>(C, v1, v2, v0, out);
        k_reduce<<<N_B, 256, 0, stream>>>(v0, out);
    }
}